// Round 5
// baseline (322.358 us; speedup 1.0000x reference)
//
#include <hip/hip_runtime.h>

#define N_NODES 100000
#define N_EDGES 320000
#define Q 4096
#define HID 128
#define DIN 256
#define NSLOT (3 * Q)   // 12288
#define CAP 64
#define NB 512
#define TPB 256
#define NTH (NB * TPB)  // 131072
#define QPB 8

__device__ __forceinline__ void gridbar(int* bar, int* gen) {
    __syncthreads();
    if (threadIdx.x == 0) {
        int g = __hip_atomic_load(gen, __ATOMIC_ACQUIRE, __HIP_MEMORY_SCOPE_AGENT);
        int a = __hip_atomic_fetch_add(bar, 1, __ATOMIC_ACQ_REL, __HIP_MEMORY_SCOPE_AGENT);
        if (a == NB - 1) {
            __hip_atomic_store(bar, 0, __ATOMIC_RELAXED, __HIP_MEMORY_SCOPE_AGENT);
            __hip_atomic_store(gen, g + 1, __ATOMIC_RELEASE, __HIP_MEMORY_SCOPE_AGENT);
        } else {
            int guard = 0;
            while (__hip_atomic_load(gen, __ATOMIC_ACQUIRE, __HIP_MEMORY_SCOPE_AGENT) == g) {
                __builtin_amdgcn_s_sleep(1);
                if (++guard > (1 << 27)) break;   // bounded: fail loud, not hung
            }
        }
    }
    __syncthreads();
}

__global__ __launch_bounds__(TPB, 2) void k_mega(
    const int* __restrict__ src, const int* __restrict__ dst,
    const float* __restrict__ ef, const float* __restrict__ bt,
    const float* __restrict__ node_ts,
    const int* __restrict__ s_idx, const int* __restrict__ p_idx,
    const int* __restrict__ n_idx,
    const float* __restrict__ time_w, const float* __restrict__ time_b,
    const float* __restrict__ W_src, const float* __restrict__ b_src,
    const float* __restrict__ W_dst, const float* __restrict__ b_dst,
    const float* __restrict__ W_out, const float* __restrict__ b_out,
    float* __restrict__ out,
    int* __restrict__ bar, int* __restrict__ gen,
    int* __restrict__ slot, int* __restrict__ cnt,
    int* __restrict__ elist, float* __restrict__ tdlist,
    float* __restrict__ h) {
    __shared__ float emb[QPB * 3][DIN];   // 24 KB, used in P4
    const int tid   = threadIdx.x;
    const int tid_g = blockIdx.x * TPB + tid;

    // ---- P0: slot = -1, cnt = 0 ----
    if (tid_g < N_NODES / 4) {
        ((int4*)slot)[tid_g] = make_int4(-1, -1, -1, -1);
    } else if (tid_g < N_NODES / 4 + NSLOT / 4) {
        ((int4*)cnt)[tid_g - N_NODES / 4] = make_int4(0, 0, 0, 0);
    }
    gridbar(bar, gen);

    // ---- P1: claim slots via CAS ----
    if (tid_g < NSLOT) {
        int t = tid_g >> 12;
        int q = tid_g & (Q - 1);
        int node = (t == 0 ? s_idx : (t == 1 ? p_idx : n_idx))[q];
        atomicCAS(&slot[node], -1, tid_g);
    }
    gridbar(bar, gen);

    // ---- P2: build per-slot edge lists ----
    for (int e = tid_g; e < N_EDGES; e += NTH) {
        int sl = slot[dst[e]];
        if (sl < 0) continue;
        float td = bt[e] - node_ts[src[e]];
        int pos = atomicAdd(&cnt[sl], 1);
        if (pos < CAP) {
            elist[sl * CAP + pos]  = e;
            tdlist[sl * CAP + pos] = td;
        }
    }
    gridbar(bar, gen);

    // ---- P3: aggregate h rows (one wave per slot, no atomics) ----
    {
        const int w = tid_g >> 6;        // wave id 0..2047
        const int l = tid_g & 63;
        const float tw0 = time_w[l],      tb0 = time_b[l];
        const float tw1 = time_w[l + 64], tb1 = time_b[l + 64];
        for (int s = w; s < NSLOT; s += NTH / 64) {
            int n = cnt[s];
            if (n > CAP) n = CAP;
            float a0 = 0.f, a1 = 0.f, a2 = 0.f, a3 = 0.f;
            for (int j = 0; j < n; ++j) {
                int   e  = elist[s * CAP + j];
                float td = tdlist[s * CAP + j];
                a0 += ef[(size_t)e * 128 + l];
                a1 += ef[(size_t)e * 128 + 64 + l];
                a2 += __cosf(td * tw0 + tb0);
                a3 += __cosf(td * tw1 + tb1);
            }
            float* hp = h + (size_t)s * DIN;
            hp[l]       = a0;
            hp[64 + l]  = a1;
            hp[128 + l] = a2;
            hp[192 + l] = a3;
        }
    }
    gridbar(bar, gen);

    // ---- P4: fused predictor (512 blocks x 8 queries) ----
    {
        const int qbase = blockIdx.x * QPB;

        for (int r = tid; r < QPB * 3 * 64; r += TPB) {
            int row = r >> 6;             // 0..23
            int c4  = r & 63;
            int t   = row >> 3;
            int q   = row & 7;
            const int* idxarr = (t == 0) ? s_idx : (t == 1) ? p_idx : n_idx;
            int node = idxarr[qbase + q];
            int sl   = slot[node];
            float4 v = *reinterpret_cast<const float4*>(h + (size_t)sl * DIN + c4 * 4);
            *reinterpret_cast<float4*>(&emb[row][c4 * 4]) = v;
        }
        __syncthreads();

        const int cg = tid & 31;
        const int j4 = cg << 2;
        const int q  = tid >> 5;          // 0..7

        float aS[4], aP[4], aN[4];
        #pragma unroll
        for (int c = 0; c < 4; ++c) {
            aS[c] = b_src[j4 + c];
            float bd = b_dst[j4 + c];
            aP[c] = bd; aN[c] = bd;
        }

        const float* e_s = emb[0 * QPB + q];
        const float* e_p = emb[1 * QPB + q];
        const float* e_n = emb[2 * QPB + q];
        const float* wsp = W_src + j4;
        const float* wdp = W_dst + j4;

        #pragma unroll 2
        for (int k = 0; k < DIN; k += 4) {
            float4 sv = *reinterpret_cast<const float4*>(e_s + k);
            float4 pv = *reinterpret_cast<const float4*>(e_p + k);
            float4 nv = *reinterpret_cast<const float4*>(e_n + k);
            #pragma unroll
            for (int kk = 0; kk < 4; ++kk) {
                float4 ws = *reinterpret_cast<const float4*>(wsp + (size_t)(k + kk) * HID);
                float4 wd = *reinterpret_cast<const float4*>(wdp + (size_t)(k + kk) * HID);
                float s1 = (&sv.x)[kk], p1 = (&pv.x)[kk], n1 = (&nv.x)[kk];
                #pragma unroll
                for (int c = 0; c < 4; ++c) {
                    float wsc = (&ws.x)[c], wdc = (&wd.x)[c];
                    aS[c] += s1 * wsc;
                    aP[c] += p1 * wdc;
                    aN[c] += n1 * wdc;
                }
            }
        }

        float rP = 0.f, rN = 0.f;
        #pragma unroll
        for (int c = 0; c < 4; ++c) {
            float wo = W_out[j4 + c];
            rP += fmaxf(aS[c] + aP[c], 0.f) * wo;
            rN += fmaxf(aS[c] + aN[c], 0.f) * wo;
        }
        #pragma unroll
        for (int off = 16; off; off >>= 1) {
            rP += __shfl_xor(rP, off);
            rN += __shfl_xor(rN, off);
        }
        if (cg == 0) {
            float bo = b_out[0];
            out[qbase + q]     = rP + bo;
            out[Q + qbase + q] = rN + bo;
        }
    }
}

// ---------------- launch ----------------

extern "C" void kernel_launch(void* const* d_in, const int* in_sizes, int n_in,
                              void* d_out, int out_size, void* d_ws, size_t ws_size,
                              hipStream_t stream) {
    const int*   src     = (const int*)d_in[0];
    const int*   dst     = (const int*)d_in[1];
    const float* ef      = (const float*)d_in[2];
    const float* bt      = (const float*)d_in[3];
    const float* node_ts = (const float*)d_in[4];
    const int*   s_idx   = (const int*)d_in[5];
    const int*   p_idx   = (const int*)d_in[6];
    const int*   n_idx   = (const int*)d_in[7];
    const float* time_w  = (const float*)d_in[8];
    const float* time_b  = (const float*)d_in[9];
    const float* W_src   = (const float*)d_in[10];
    const float* b_src   = (const float*)d_in[11];
    const float* W_dst   = (const float*)d_in[12];
    const float* b_dst   = (const float*)d_in[13];
    const float* W_out   = (const float*)d_in[14];
    const float* b_out   = (const float*)d_in[15];
    float*       out     = (float*)d_out;

    // workspace layout (bytes)
    char* ws = (char*)d_ws;
    int*   bar    = (int*)ws;                         // [1]
    int*   gen    = (int*)(ws + 4);                   // [1]
    int*   slot   = (int*)(ws + 1024);                // [100000]
    int*   cnt    = (int*)(ws + 512 * 1024);          // [12288]
    int*   elist  = (int*)(ws + 1024 * 1024);         // [12288*64] = 3 MB
    float* tdlist = (float*)(ws + 5 * 1024 * 1024);   // [12288*64] = 3 MB
    float* h      = (float*)(ws + 9 * 1024 * 1024);   // [12288*256] = 12.6 MB

    hipMemsetAsync(ws, 0, 8, stream);                 // bar = gen = 0
    k_mega<<<NB, TPB, 0, stream>>>(src, dst, ef, bt, node_ts,
                                   s_idx, p_idx, n_idx, time_w, time_b,
                                   W_src, b_src, W_dst, b_dst, W_out, b_out,
                                   out, bar, gen, slot, cnt, elist, tdlist, h);
}

// Round 8
// 79.079 us; speedup vs baseline: 4.0764x; 4.0764x over previous
//
#include <hip/hip_runtime.h>

#define N_NODES 100000
#define N_EDGES 320000
#define Q 4096
#define HID 128
#define DIN 256
#define NSLOT (3 * Q)   // 12288
#define CAP 64
#define QPB 8

// ---------------- K1: slot = -1 ----------------
__global__ __launch_bounds__(256) void k_init(int4* __restrict__ slot4) {
    int i = blockIdx.x * 256 + threadIdx.x;
    if (i < N_NODES / 4) slot4[i] = make_int4(-1, -1, -1, -1);
}

// ---------------- K2: claim slots via CAS + zero cnt ----------------
__global__ __launch_bounds__(256) void k_claim(const int* __restrict__ s_idx,
                                               const int* __restrict__ p_idx,
                                               const int* __restrict__ n_idx,
                                               int* __restrict__ slot,
                                               int* __restrict__ cnt) {
    int i = blockIdx.x * 256 + threadIdx.x;   // 0 .. NSLOT-1
    cnt[i] = 0;
    int t = i >> 12;
    int q = i & (Q - 1);
    int node = (t == 0 ? s_idx : (t == 1 ? p_idx : n_idx))[q];
    atomicCAS(&slot[node], -1, i);
}

// ---------------- K3: build per-slot edge lists ----------------
__global__ __launch_bounds__(256) void k_build(
    const int* __restrict__ src, const int* __restrict__ dst,
    const float* __restrict__ bt, const float* __restrict__ node_ts,
    const int* __restrict__ slot, int* __restrict__ cnt,
    int* __restrict__ elist, float* __restrict__ tdlist) {
    int e = blockIdx.x * 256 + threadIdx.x;
    if (e >= N_EDGES) return;
    int sl = slot[dst[e]];
    if (sl < 0) return;
    float td = bt[e] - node_ts[src[e]];
    int pos = atomicAdd(&cnt[sl], 1);
    if (pos < CAP) {
        elist[sl * CAP + pos]  = e;
        tdlist[sl * CAP + pos] = td;
    }
}

// ---------------- K4: fused emb-build + predictor ----------------
// 512 blocks x 256 threads, 8 queries per block.
__global__ __launch_bounds__(256) void k_fused(
    const int* __restrict__ s_idx, const int* __restrict__ p_idx,
    const int* __restrict__ n_idx, const int* __restrict__ slot,
    const int* __restrict__ cnt, const int* __restrict__ elist,
    const float* __restrict__ tdlist, const float* __restrict__ ef,
    const float* __restrict__ time_w, const float* __restrict__ time_b,
    const float* __restrict__ W_src, const float* __restrict__ b_src,
    const float* __restrict__ W_dst, const float* __restrict__ b_dst,
    const float* __restrict__ W_out, const float* __restrict__ b_out,
    float* __restrict__ out) {
    __shared__ float emb[QPB * 3][DIN];   // 24 KB; row = t*QPB + q
    const int tid   = threadIdx.x;
    const int qbase = blockIdx.x * QPB;

    // ---- build emb rows from edge lists (one wave per row, 6 rounds) ----
    {
        const int w = tid >> 6;           // wave 0..3
        const int l = tid & 63;
        const float tw0 = time_w[l],      tb0 = time_b[l];
        const float tw1 = time_w[l + 64], tb1 = time_b[l + 64];
        for (int row = w; row < QPB * 3; row += 4) {
            int t = row >> 3;             // 0..2
            int q = row & 7;
            const int* idxarr = (t == 0) ? s_idx : (t == 1) ? p_idx : n_idx;
            int node = idxarr[qbase + q];
            int sl   = slot[node];        // >= 0 by construction
            int n    = cnt[sl];
            if (n > CAP) n = CAP;
            float a0 = 0.f, a1 = 0.f, a2 = 0.f, a3 = 0.f;
            for (int j = 0; j < n; ++j) {
                int   e  = elist[sl * CAP + j];
                float td = tdlist[sl * CAP + j];
                a0 += ef[(size_t)e * 128 + l];
                a1 += ef[(size_t)e * 128 + 64 + l];
                a2 += __cosf(td * tw0 + tb0);
                a3 += __cosf(td * tw1 + tb1);
            }
            emb[row][l]       = a0;
            emb[row][64 + l]  = a1;
            emb[row][128 + l] = a2;
            emb[row][192 + l] = a3;
        }
    }
    __syncthreads();

    // ---- GEMM + relu + W_out dot (proven in R5 P4) ----
    const int cg = tid & 31;
    const int j4 = cg << 2;
    const int q  = tid >> 5;              // 0..7

    float aS[4], aP[4], aN[4];
    #pragma unroll
    for (int c = 0; c < 4; ++c) {
        aS[c] = b_src[j4 + c];
        float bd = b_dst[j4 + c];
        aP[c] = bd; aN[c] = bd;
    }

    const float* e_s = emb[0 * QPB + q];
    const float* e_p = emb[1 * QPB + q];
    const float* e_n = emb[2 * QPB + q];
    const float* wsp = W_src + j4;
    const float* wdp = W_dst + j4;

    #pragma unroll 2
    for (int k = 0; k < DIN; k += 4) {
        float4 sv = *reinterpret_cast<const float4*>(e_s + k);
        float4 pv = *reinterpret_cast<const float4*>(e_p + k);
        float4 nv = *reinterpret_cast<const float4*>(e_n + k);
        #pragma unroll
        for (int kk = 0; kk < 4; ++kk) {
            float4 ws = *reinterpret_cast<const float4*>(wsp + (size_t)(k + kk) * HID);
            float4 wd = *reinterpret_cast<const float4*>(wdp + (size_t)(k + kk) * HID);
            float s1 = (&sv.x)[kk], p1 = (&pv.x)[kk], n1 = (&nv.x)[kk];
            #pragma unroll
            for (int c = 0; c < 4; ++c) {
                float wsc = (&ws.x)[c], wdc = (&wd.x)[c];
                aS[c] += s1 * wsc;
                aP[c] += p1 * wdc;
                aN[c] += n1 * wdc;
            }
        }
    }

    float rP = 0.f, rN = 0.f;
    #pragma unroll
    for (int c = 0; c < 4; ++c) {
        float wo = W_out[j4 + c];
        rP += fmaxf(aS[c] + aP[c], 0.f) * wo;
        rN += fmaxf(aS[c] + aN[c], 0.f) * wo;
    }
    #pragma unroll
    for (int off = 16; off; off >>= 1) {
        rP += __shfl_xor(rP, off);
        rN += __shfl_xor(rN, off);
    }
    if (cg == 0) {
        float bo = b_out[0];
        out[qbase + q]     = rP + bo;
        out[Q + qbase + q] = rN + bo;
    }
}

// ---------------- launch ----------------

extern "C" void kernel_launch(void* const* d_in, const int* in_sizes, int n_in,
                              void* d_out, int out_size, void* d_ws, size_t ws_size,
                              hipStream_t stream) {
    const int*   src     = (const int*)d_in[0];
    const int*   dst     = (const int*)d_in[1];
    const float* ef      = (const float*)d_in[2];
    const float* bt      = (const float*)d_in[3];
    const float* node_ts = (const float*)d_in[4];
    const int*   s_idx   = (const int*)d_in[5];
    const int*   p_idx   = (const int*)d_in[6];
    const int*   n_idx   = (const int*)d_in[7];
    const float* time_w  = (const float*)d_in[8];
    const float* time_b  = (const float*)d_in[9];
    const float* W_src   = (const float*)d_in[10];
    const float* b_src   = (const float*)d_in[11];
    const float* W_dst   = (const float*)d_in[12];
    const float* b_dst   = (const float*)d_in[13];
    const float* W_out   = (const float*)d_in[14];
    const float* b_out   = (const float*)d_in[15];
    float*       out     = (float*)d_out;

    // workspace layout (bytes)
    char* ws = (char*)d_ws;
    int*   slot   = (int*)ws;                         // [100000]
    int*   cnt    = (int*)(ws + 512 * 1024);          // [12288]
    int*   elist  = (int*)(ws + 1024 * 1024);         // [12288*64] = 3 MB
    float* tdlist = (float*)(ws + 5 * 1024 * 1024);   // [12288*64] = 3 MB

    k_init<<<(N_NODES / 4 + 255) / 256, 256, 0, stream>>>((int4*)slot);
    k_claim<<<NSLOT / 256, 256, 0, stream>>>(s_idx, p_idx, n_idx, slot, cnt);
    k_build<<<(N_EDGES + 255) / 256, 256, 0, stream>>>(src, dst, bt, node_ts,
                                                       slot, cnt, elist, tdlist);
    k_fused<<<Q / QPB, 256, 0, stream>>>(s_idx, p_idx, n_idx, slot, cnt,
                                         elist, tdlist, ef, time_w, time_b,
                                         W_src, b_src, W_dst, b_dst,
                                         W_out, b_out, out);
}

// Round 9
// 75.388 us; speedup vs baseline: 4.2760x; 1.0490x over previous
//
#include <hip/hip_runtime.h>

#define N_NODES 100000
#define N_EDGES 320000
#define Q 4096
#define HID 128
#define DIN 256
#define NSLOT (3 * Q)   // 12288
#define CAP 64
#define QPB 8

// ---------------- K1: slot = -1 ----------------
__global__ __launch_bounds__(256) void k_init(int4* __restrict__ slot4) {
    int i = blockIdx.x * 256 + threadIdx.x;
    if (i < N_NODES / 4) slot4[i] = make_int4(-1, -1, -1, -1);
}

// ---------------- K2: claim slots via CAS + zero cnt ----------------
__global__ __launch_bounds__(256) void k_claim(const int* __restrict__ s_idx,
                                               const int* __restrict__ p_idx,
                                               const int* __restrict__ n_idx,
                                               int* __restrict__ slot,
                                               int* __restrict__ cnt) {
    int i = blockIdx.x * 256 + threadIdx.x;   // 0 .. NSLOT-1
    cnt[i] = 0;
    int t = i >> 12;
    int q = i & (Q - 1);
    int node = (t == 0 ? s_idx : (t == 1 ? p_idx : n_idx))[q];
    atomicCAS(&slot[node], -1, i);
}

// ---------------- K3: build per-slot edge lists (int2 = {e, td}) -------
__global__ __launch_bounds__(256) void k_build(
    const int* __restrict__ src, const int* __restrict__ dst,
    const float* __restrict__ bt, const float* __restrict__ node_ts,
    const int* __restrict__ slot, int* __restrict__ cnt,
    int2* __restrict__ edata) {
    int e = blockIdx.x * 256 + threadIdx.x;
    if (e >= N_EDGES) return;
    int sl = slot[dst[e]];
    if (sl < 0) return;
    float td = bt[e] - node_ts[src[e]];
    int pos = atomicAdd(&cnt[sl], 1);
    if (pos < CAP) edata[sl * CAP + pos] = make_int2(e, __float_as_int(td));
}

// ---------------- K4: fused emb-build + predictor ----------------
// 512 blocks x 256 threads, 8 queries per block.
// emb-build: wave w owns rows {w, w+4, ..., w+20} processed as 3 pairs,
// lane l covers cols {2l, 2l+1} (float2 loads/stores).
__global__ __launch_bounds__(256) void k_fused(
    const int* __restrict__ s_idx, const int* __restrict__ p_idx,
    const int* __restrict__ n_idx, const int* __restrict__ slot,
    const int* __restrict__ cnt, const int2* __restrict__ edata,
    const float* __restrict__ ef,
    const float* __restrict__ time_w, const float* __restrict__ time_b,
    const float* __restrict__ W_src, const float* __restrict__ b_src,
    const float* __restrict__ W_dst, const float* __restrict__ b_dst,
    const float* __restrict__ W_out, const float* __restrict__ b_out,
    float* __restrict__ out) {
    __shared__ float emb[QPB * 3][DIN];   // 24 KB; row = t*QPB + q
    const int tid   = threadIdx.x;
    const int qbase = blockIdx.x * QPB;

    // ---- build emb rows from edge lists, pair-interleaved ----
    {
        const int w = tid >> 6;           // wave 0..3
        const int l = tid & 63;
        const float2 tw = *reinterpret_cast<const float2*>(time_w + 2 * l);
        const float2 tb = *reinterpret_cast<const float2*>(time_b + 2 * l);
        #pragma unroll
        for (int pr = 0; pr < 3; ++pr) {
            const int rowA = w + pr * 8;
            const int rowB = rowA + 4;
            int tA = rowA >> 3, qA = rowA & 7;
            int tB = rowB >> 3, qB = rowB & 7;
            const int* ia = (tA == 0) ? s_idx : (tA == 1) ? p_idx : n_idx;
            const int* ib = (tB == 0) ? s_idx : (tB == 1) ? p_idx : n_idx;
            int slA = slot[ia[qbase + qA]];
            int slB = slot[ib[qbase + qB]];
            int nA = cnt[slA]; if (nA > CAP) nA = CAP;
            int nB = cnt[slB]; if (nB > CAP) nB = CAP;
            const int2* eA = edata + (size_t)slA * CAP;
            const int2* eB = edata + (size_t)slB * CAP;
            float2 aA = {0.f, 0.f}, cA = {0.f, 0.f};
            float2 aB = {0.f, 0.f}, cB = {0.f, 0.f};
            int nmax = nA > nB ? nA : nB;
            for (int j = 0; j < nmax; ++j) {
                bool doA = j < nA, doB = j < nB;
                int2 edA, edB;
                float2 vA, vB;
                if (doA) edA = eA[j];
                if (doB) edB = eB[j];
                if (doA) vA = *reinterpret_cast<const float2*>(ef + (size_t)edA.x * 128 + 2 * l);
                if (doB) vB = *reinterpret_cast<const float2*>(ef + (size_t)edB.x * 128 + 2 * l);
                if (doA) {
                    float td = __int_as_float(edA.y);
                    aA.x += vA.x;  aA.y += vA.y;
                    cA.x += __cosf(td * tw.x + tb.x);
                    cA.y += __cosf(td * tw.y + tb.y);
                }
                if (doB) {
                    float td = __int_as_float(edB.y);
                    aB.x += vB.x;  aB.y += vB.y;
                    cB.x += __cosf(td * tw.x + tb.x);
                    cB.y += __cosf(td * tw.y + tb.y);
                }
            }
            *reinterpret_cast<float2*>(&emb[rowA][2 * l])       = aA;
            *reinterpret_cast<float2*>(&emb[rowA][128 + 2 * l]) = cA;
            *reinterpret_cast<float2*>(&emb[rowB][2 * l])       = aB;
            *reinterpret_cast<float2*>(&emb[rowB][128 + 2 * l]) = cB;
        }
    }
    __syncthreads();

    // ---- GEMM + relu + W_out dot (proven R5/R8) ----
    const int cg = tid & 31;
    const int j4 = cg << 2;
    const int q  = tid >> 5;              // 0..7

    float aS[4], aP[4], aN[4];
    #pragma unroll
    for (int c = 0; c < 4; ++c) {
        aS[c] = b_src[j4 + c];
        float bd = b_dst[j4 + c];
        aP[c] = bd; aN[c] = bd;
    }

    const float* e_s = emb[0 * QPB + q];
    const float* e_p = emb[1 * QPB + q];
    const float* e_n = emb[2 * QPB + q];
    const float* wsp = W_src + j4;
    const float* wdp = W_dst + j4;

    #pragma unroll 2
    for (int k = 0; k < DIN; k += 4) {
        float4 sv = *reinterpret_cast<const float4*>(e_s + k);
        float4 pv = *reinterpret_cast<const float4*>(e_p + k);
        float4 nv = *reinterpret_cast<const float4*>(e_n + k);
        #pragma unroll
        for (int kk = 0; kk < 4; ++kk) {
            float4 ws = *reinterpret_cast<const float4*>(wsp + (size_t)(k + kk) * HID);
            float4 wd = *reinterpret_cast<const float4*>(wdp + (size_t)(k + kk) * HID);
            float s1 = (&sv.x)[kk], p1 = (&pv.x)[kk], n1 = (&nv.x)[kk];
            #pragma unroll
            for (int c = 0; c < 4; ++c) {
                float wsc = (&ws.x)[c], wdc = (&wd.x)[c];
                aS[c] += s1 * wsc;
                aP[c] += p1 * wdc;
                aN[c] += n1 * wdc;
            }
        }
    }

    float rP = 0.f, rN = 0.f;
    #pragma unroll
    for (int c = 0; c < 4; ++c) {
        float wo = W_out[j4 + c];
        rP += fmaxf(aS[c] + aP[c], 0.f) * wo;
        rN += fmaxf(aS[c] + aN[c], 0.f) * wo;
    }
    #pragma unroll
    for (int off = 16; off; off >>= 1) {
        rP += __shfl_xor(rP, off);
        rN += __shfl_xor(rN, off);
    }
    if (cg == 0) {
        float bo = b_out[0];
        out[qbase + q]     = rP + bo;
        out[Q + qbase + q] = rN + bo;
    }
}

// ---------------- launch ----------------

extern "C" void kernel_launch(void* const* d_in, const int* in_sizes, int n_in,
                              void* d_out, int out_size, void* d_ws, size_t ws_size,
                              hipStream_t stream) {
    const int*   src     = (const int*)d_in[0];
    const int*   dst     = (const int*)d_in[1];
    const float* ef      = (const float*)d_in[2];
    const float* bt      = (const float*)d_in[3];
    const float* node_ts = (const float*)d_in[4];
    const int*   s_idx   = (const int*)d_in[5];
    const int*   p_idx   = (const int*)d_in[6];
    const int*   n_idx   = (const int*)d_in[7];
    const float* time_w  = (const float*)d_in[8];
    const float* time_b  = (const float*)d_in[9];
    const float* W_src   = (const float*)d_in[10];
    const float* b_src   = (const float*)d_in[11];
    const float* W_dst   = (const float*)d_in[12];
    const float* b_dst   = (const float*)d_in[13];
    const float* W_out   = (const float*)d_in[14];
    const float* b_out   = (const float*)d_in[15];
    float*       out     = (float*)d_out;

    // workspace layout (bytes)
    char* ws = (char*)d_ws;
    int*   slot  = (int*)ws;                          // [100000]
    int*   cnt   = (int*)(ws + 512 * 1024);           // [12288]
    int2*  edata = (int2*)(ws + 1024 * 1024);         // [12288*64] int2 = 6.3 MB

    k_init<<<(N_NODES / 4 + 255) / 256, 256, 0, stream>>>((int4*)slot);
    k_claim<<<NSLOT / 256, 256, 0, stream>>>(s_idx, p_idx, n_idx, slot, cnt);
    k_build<<<(N_EDGES + 255) / 256, 256, 0, stream>>>(src, dst, bt, node_ts,
                                                       slot, cnt, edata);
    k_fused<<<Q / QPB, 256, 0, stream>>>(s_idx, p_idx, n_idx, slot, cnt,
                                         edata, ef, time_w, time_b,
                                         W_src, b_src, W_dst, b_dst,
                                         W_out, b_out, out);
}

// Round 10
// 60.055 us; speedup vs baseline: 5.3677x; 1.2553x over previous
//
#include <hip/hip_runtime.h>

#define N_NODES 100000
#define N_EDGES 320000
#define Q 4096
#define HID 128
#define DIN 256
#define EMB_LD 260      // DIN + 4 pad: rows hit distinct LDS bank groups
#define NSLOT (3 * Q)   // 12288
#define CAP 64
#define QPB 8

// ---------------- K1: slot = -1 ----------------
__global__ __launch_bounds__(256) void k_init(int4* __restrict__ slot4) {
    int i = blockIdx.x * 256 + threadIdx.x;
    if (i < N_NODES / 4) slot4[i] = make_int4(-1, -1, -1, -1);
}

// ---------------- K2: claim slots via CAS + zero cnt ----------------
__global__ __launch_bounds__(256) void k_claim(const int* __restrict__ s_idx,
                                               const int* __restrict__ p_idx,
                                               const int* __restrict__ n_idx,
                                               int* __restrict__ slot,
                                               int* __restrict__ cnt) {
    int i = blockIdx.x * 256 + threadIdx.x;   // 0 .. NSLOT-1
    cnt[i] = 0;
    int t = i >> 12;
    int q = i & (Q - 1);
    int node = (t == 0 ? s_idx : (t == 1 ? p_idx : n_idx))[q];
    atomicCAS(&slot[node], -1, i);
}

// ---------------- K3: build per-slot edge lists (int2 = {e, td}) -------
__global__ __launch_bounds__(256) void k_build(
    const int* __restrict__ src, const int* __restrict__ dst,
    const float* __restrict__ bt, const float* __restrict__ node_ts,
    const int* __restrict__ slot, int* __restrict__ cnt,
    int2* __restrict__ edata) {
    int e = blockIdx.x * 256 + threadIdx.x;
    if (e >= N_EDGES) return;
    int sl = slot[dst[e]];
    if (sl < 0) return;
    float td = bt[e] - node_ts[src[e]];
    int pos = atomicAdd(&cnt[sl], 1);
    if (pos < CAP) edata[sl * CAP + pos] = make_int2(e, __float_as_int(td));
}

// ---------------- K4: fused emb-build + predictor ----------------
// 512 blocks x 256 threads (4 waves), 8 queries per block.
// Phase A (gather): wave w owns rows {w, w+4, ..., w+20}; within wave
//   j=lane>>4 is the edge slot (4 edges in flight), g=lane&15 the col group.
// Phase B (GEMM): wave w owns cols [32w,32w+32); lane = (q=lane>>3, g2=lane&7).
__global__ __launch_bounds__(256) void k_fused(
    const int* __restrict__ s_idx, const int* __restrict__ p_idx,
    const int* __restrict__ n_idx, const int* __restrict__ slot,
    const int* __restrict__ cnt, const int2* __restrict__ edata,
    const float* __restrict__ ef,
    const float* __restrict__ time_w, const float* __restrict__ time_b,
    const float* __restrict__ W_src, const float* __restrict__ b_src,
    const float* __restrict__ W_dst, const float* __restrict__ b_dst,
    const float* __restrict__ W_out, const float* __restrict__ b_out,
    float* __restrict__ out) {
    __shared__ float emb[QPB * 3][EMB_LD];   // ~25 KB
    __shared__ float pP[QPB][4], pN[QPB][4];
    const int tid   = threadIdx.x;
    const int qbase = blockIdx.x * QPB;
    const int w     = tid >> 6;
    const int lane  = tid & 63;

    // ---- Phase A: lane-parallel gather ----
    {
        const int j = lane >> 4;          // edge slot 0..3
        const int g = lane & 15;          // col group 0..15
        const float4 tw0 = *reinterpret_cast<const float4*>(time_w + 8 * g);
        const float4 tw1 = *reinterpret_cast<const float4*>(time_w + 8 * g + 4);
        const float4 tb0 = *reinterpret_cast<const float4*>(time_b + 8 * g);
        const float4 tb1 = *reinterpret_cast<const float4*>(time_b + 8 * g + 4);
        for (int row = w; row < QPB * 3; row += 4) {
            int t = row >> 3, q = row & 7;
            const int* ia = (t == 0) ? s_idx : (t == 1) ? p_idx : n_idx;
            int sl = slot[ia[qbase + q]];
            int n = cnt[sl]; if (n > CAP) n = CAP;
            float4 accA = {0.f, 0.f, 0.f, 0.f}, accB = {0.f, 0.f, 0.f, 0.f};
            float4 tcA  = {0.f, 0.f, 0.f, 0.f}, tcB  = {0.f, 0.f, 0.f, 0.f};
            for (int jb = j; jb < n; jb += 4) {
                int2 ed = edata[(size_t)sl * CAP + jb];
                const float* rp = ef + (size_t)ed.x * 128;
                float4 vA = *reinterpret_cast<const float4*>(rp + 4 * g);
                float4 vB = *reinterpret_cast<const float4*>(rp + 64 + 4 * g);
                float td = __int_as_float(ed.y);
                accA.x += vA.x; accA.y += vA.y; accA.z += vA.z; accA.w += vA.w;
                accB.x += vB.x; accB.y += vB.y; accB.z += vB.z; accB.w += vB.w;
                tcA.x += __cosf(td * tw0.x + tb0.x);
                tcA.y += __cosf(td * tw0.y + tb0.y);
                tcA.z += __cosf(td * tw0.z + tb0.z);
                tcA.w += __cosf(td * tw0.w + tb0.w);
                tcB.x += __cosf(td * tw1.x + tb1.x);
                tcB.y += __cosf(td * tw1.y + tb1.y);
                tcB.z += __cosf(td * tw1.z + tb1.z);
                tcB.w += __cosf(td * tw1.w + tb1.w);
            }
            // reduce over edge slots j (lanes g, 16+g, 32+g, 48+g)
#define RED2(v) { v += __shfl_xor(v, 16); v += __shfl_xor(v, 32); }
            RED2(accA.x) RED2(accA.y) RED2(accA.z) RED2(accA.w)
            RED2(accB.x) RED2(accB.y) RED2(accB.z) RED2(accB.w)
            RED2(tcA.x)  RED2(tcA.y)  RED2(tcA.z)  RED2(tcA.w)
            RED2(tcB.x)  RED2(tcB.y)  RED2(tcB.z)  RED2(tcB.w)
#undef RED2
            if (j == 0) {
                *reinterpret_cast<float4*>(&emb[row][4 * g])       = accA;
                *reinterpret_cast<float4*>(&emb[row][64 + 4 * g])  = accB;
                *reinterpret_cast<float4*>(&emb[row][128 + 8 * g]) = tcA;
                *reinterpret_cast<float4*>(&emb[row][132 + 8 * g]) = tcB;
            }
        }
    }
    __syncthreads();

    // ---- Phase B: GEMM + relu + W_out dot ----
    {
        const int q       = lane >> 3;        // 0..7
        const int g2      = lane & 7;         // 0..7
        const int colbase = 32 * w + 4 * g2;  // wave covers 32 cols

        float4 bs = *reinterpret_cast<const float4*>(b_src + colbase);
        float4 bd = *reinterpret_cast<const float4*>(b_dst + colbase);
        float aS[4] = {bs.x, bs.y, bs.z, bs.w};
        float aP[4] = {bd.x, bd.y, bd.z, bd.w};
        float aN[4] = {bd.x, bd.y, bd.z, bd.w};

        const float* e_s = emb[q];
        const float* e_p = emb[QPB + q];
        const float* e_n = emb[2 * QPB + q];

        for (int k = 0; k < DIN; k += 4) {
            float4 sv = *reinterpret_cast<const float4*>(e_s + k);
            float4 pv = *reinterpret_cast<const float4*>(e_p + k);
            float4 nv = *reinterpret_cast<const float4*>(e_n + k);
            #pragma unroll
            for (int kk = 0; kk < 4; ++kk) {
                float4 ws = *reinterpret_cast<const float4*>(W_src + (size_t)(k + kk) * HID + colbase);
                float4 wd = *reinterpret_cast<const float4*>(W_dst + (size_t)(k + kk) * HID + colbase);
                float s1 = (&sv.x)[kk], p1 = (&pv.x)[kk], n1 = (&nv.x)[kk];
                #pragma unroll
                for (int c = 0; c < 4; ++c) {
                    float wsc = (&ws.x)[c], wdc = (&wd.x)[c];
                    aS[c] += s1 * wsc;
                    aP[c] += p1 * wdc;
                    aN[c] += n1 * wdc;
                }
            }
        }

        float4 wo = *reinterpret_cast<const float4*>(W_out + colbase);
        float rP = 0.f, rN = 0.f;
        #pragma unroll
        for (int c = 0; c < 4; ++c) {
            float woc = (&wo.x)[c];
            rP += fmaxf(aS[c] + aP[c], 0.f) * woc;
            rN += fmaxf(aS[c] + aN[c], 0.f) * woc;
        }
        rP += __shfl_xor(rP, 1); rP += __shfl_xor(rP, 2); rP += __shfl_xor(rP, 4);
        rN += __shfl_xor(rN, 1); rN += __shfl_xor(rN, 2); rN += __shfl_xor(rN, 4);
        if (g2 == 0) { pP[q][w] = rP; pN[q][w] = rN; }
    }
    __syncthreads();

    if (tid < QPB) {
        float bo = b_out[0];
        out[qbase + tid]     = pP[tid][0] + pP[tid][1] + pP[tid][2] + pP[tid][3] + bo;
        out[Q + qbase + tid] = pN[tid][0] + pN[tid][1] + pN[tid][2] + pN[tid][3] + bo;
    }
}

// ---------------- launch ----------------

extern "C" void kernel_launch(void* const* d_in, const int* in_sizes, int n_in,
                              void* d_out, int out_size, void* d_ws, size_t ws_size,
                              hipStream_t stream) {
    const int*   src     = (const int*)d_in[0];
    const int*   dst     = (const int*)d_in[1];
    const float* ef      = (const float*)d_in[2];
    const float* bt      = (const float*)d_in[3];
    const float* node_ts = (const float*)d_in[4];
    const int*   s_idx   = (const int*)d_in[5];
    const int*   p_idx   = (const int*)d_in[6];
    const int*   n_idx   = (const int*)d_in[7];
    const float* time_w  = (const float*)d_in[8];
    const float* time_b  = (const float*)d_in[9];
    const float* W_src   = (const float*)d_in[10];
    const float* b_src   = (const float*)d_in[11];
    const float* W_dst   = (const float*)d_in[12];
    const float* b_dst   = (const float*)d_in[13];
    const float* W_out   = (const float*)d_in[14];
    const float* b_out   = (const float*)d_in[15];
    float*       out     = (float*)d_out;

    // workspace layout (bytes)
    char* ws = (char*)d_ws;
    int*   slot  = (int*)ws;                          // [100000]
    int*   cnt   = (int*)(ws + 512 * 1024);           // [12288]
    int2*  edata = (int2*)(ws + 1024 * 1024);         // [12288*64] int2 = 6.3 MB

    k_init<<<(N_NODES / 4 + 255) / 256, 256, 0, stream>>>((int4*)slot);
    k_claim<<<NSLOT / 256, 256, 0, stream>>>(s_idx, p_idx, n_idx, slot, cnt);
    k_build<<<(N_EDGES + 255) / 256, 256, 0, stream>>>(src, dst, bt, node_ts,
                                                       slot, cnt, edata);
    k_fused<<<Q / QPB, 256, 0, stream>>>(s_idx, p_idx, n_idx, slot, cnt,
                                         edata, ef, time_w, time_b,
                                         W_src, b_src, W_dst, b_dst,
                                         W_out, b_out, out);
}